// Round 12
// baseline (286.197 us; speedup 1.0000x reference)
//
#include <hip/hip_runtime.h>
#include <hip/hip_bf16.h>

// Fused GAT (2 layers) + attention pooling + classifier for MI355X.
// Round 12: identical to round 11 (GPU acquisition timed out; reshape
// unbenched). gemm_split 128x128/4w/dbuf (64 KB LDS => 2 blocks/CU
// co-resident; other block's MFMA hides this block's barrier drain, m114).
// Grid 1024, bijective XCD-chunked swizzle, bn-fastest.
// bf16x3 split GEMM: C = A_hi.B_hi + A_lo.B_hi + A_hi.B_lo.

#define NGRAPH 2048
#define NPG    16
#define EPG    128
#define ETOT   (EPG + NPG)      // 144 edges incl. self loops
#define NNODES (NGRAPH * NPG)   // 32768
#define NEDGE  (NGRAPH * EPG)   // 262144
#define CH     256              // per-head channels
#define HC     512              // HEADS * CH
#define NEG    0.2f

#define KTILES 12               // K_eff = 3 planes * 256 / BK64 = 12

typedef __attribute__((ext_vector_type(8))) short bf16x8;
typedef __attribute__((ext_vector_type(4))) float f32x4;

__device__ __forceinline__ ushort f2bf(float f) {   // fp32 -> bf16 bits, RNE
    uint u = __float_as_uint(f);
    u += 0x7fffu + ((u >> 16) & 1u);
    return (ushort)(u >> 16);
}
__device__ __forceinline__ float bf2f(ushort b) {
    return __uint_as_float(((uint)b) << 16);
}
// monotone float<->uint key for atomicMax over arbitrary-sign floats
__device__ __forceinline__ uint fkey(float f) {
    uint u = __float_as_uint(f);
    return u ^ (uint)(((int)u >> 31) | (int)0x80000000u);
}
__device__ __forceinline__ float funkey(uint k) {
    uint u = (k & 0x80000000u) ? (k ^ 0x80000000u) : ~k;
    return __uint_as_float(u);
}

__device__ __forceinline__ void gll16(const void* g, void* l) {
    // async global->LDS, 16B/lane; LDS dest = wave-uniform base + lane*16
    __builtin_amdgcn_global_load_lds(
        (const __attribute__((address_space(1))) unsigned int*)g,
        (__attribute__((address_space(3))) unsigned int*)l, 16, 0, 0);
}

// ---------------------------------------------------------------------------
// fp32 [rows,256] -> split bf16 [rows,512]: hi plane at k<256, lo at k>=256
// ---------------------------------------------------------------------------
__global__ __launch_bounds__(256) void convert_split(
    const float* __restrict__ src, ushort* __restrict__ dst, int rows)
{
    int i = blockIdx.x * 256 + threadIdx.x;      // one thread per 4 elements
    if (i >= rows * 64) return;
    int r = i >> 6, c4 = (i & 63) << 2;
    float4 v = *(const float4*)&src[(size_t)r * 256 + c4];
    float vv[4] = {v.x, v.y, v.z, v.w};
    ushort4 hi, lo;
    ushort* hp = (ushort*)&hi; ushort* lp = (ushort*)&lo;
    #pragma unroll
    for (int q = 0; q < 4; ++q) {
        hp[q] = f2bf(vv[q]);
        lp[q] = f2bf(vv[q] - bf2f(hp[q]));
    }
    *(ushort4*)&dst[(size_t)r * 512 + c4]       = hi;
    *(ushort4*)&dst[(size_t)r * 512 + 256 + c4] = lo;
}

// ---------------------------------------------------------------------------
// C[M,512] (f32) = split3( A2[M,512]bf16 , B2[512,512]bf16 )
// BM=BN=128, BK=64, 256 threads (4 waves, 2Mx2N), wave tile 64x64.
// K-tiles 0..3: A_hi*B_hi, 4..7: A_lo*B_hi, 8..11: A_hi*B_lo.
// 2-phase dbuf schedule; 64 KB LDS -> 2 blocks/CU co-resident (the other
// block's MFMA hides this block's stage+barrier drain).
// ---------------------------------------------------------------------------
__global__ __launch_bounds__(256, 2) void gemm_split(
    const ushort* __restrict__ A2, const ushort* __restrict__ B2,
    float* __restrict__ C)
{
    __shared__ ushort Ash[2 * 128 * 64];   // 32 KB (double-buffered)
    __shared__ ushort Bsh[2 * 128 * 64];   // 32 KB

    const int t  = threadIdx.x;
    const int w  = t >> 6, l = t & 63;
    const int wm = w >> 1, wn = w & 1;     // 2 x 2 wave grid, wave tile 64x64
    const int lr = l & 15;
    const int lk = l >> 4;                 // k sub-chunk (0..3) -> 8 elems each

    // bijective XCD-chunked swizzle: nwg=1024 (%8==0). XCD x gets work-ids
    // [x*128, x*128+128) = 32 bm-panels x 4 bn -> A panel stays in-XCD.
    const int work = (blockIdx.x & 7) * 128 + (blockIdx.x >> 3);
    const int bn = (work & 3) << 7;        // 4 col tiles (bn fastest)
    const int bm = (work >> 2) << 7;       // 256 row tiles

    f32x4 acc[4][4];
    #pragma unroll
    for (int i = 0; i < 4; ++i)
        #pragma unroll
        for (int j = 0; j < 4; ++j)
            acc[i][j] = (f32x4){0.f, 0.f, 0.f, 0.f};

    auto stage = [&](int kt, int buf) {
        const int p    = kt >> 2;
        const int kk   = (kt & 3) << 6;               // 0,64,128,192
        const int aoff = ((p == 1) ? 256 : 0) + kk;   // A: lo plane on pass 1
        const int boff = ((p == 2) ? 256 : 0) + kk;   // B: lo plane on pass 2
        ushort* ab = Ash + buf * (128 * 64);
        ushort* bb = Bsh + buf * (128 * 64);
        #pragma unroll
        for (int i = 0; i < 4; ++i) {
            const int ci = i * 256 + t;               // 16B chunk id, 0..1023
            const int r  = ci >> 3;                   // tile row (8 chunks/row)
            const int cc = (ci & 7) << 3;             // k-elem offset in row
            gll16(A2 + (size_t)(bm + r) * 512 + aoff + cc, ab + ci * 8);
            gll16(B2 + (size_t)(bn + r) * 512 + boff + cc, bb + ci * 8);
        }
    };

    stage(0, 0);
    __syncthreads();
    for (int kt = 0; kt < KTILES; ++kt) {
        if (kt + 1 < KTILES) stage(kt + 1, (kt + 1) & 1);  // prefetch overlaps
        const ushort* ab = Ash + (kt & 1) * (128 * 64);
        const ushort* bb = Bsh + (kt & 1) * (128 * 64);
        #pragma unroll
        for (int ks = 0; ks < 2; ++ks) {
            bf16x8 af[4], bfr[4];
            #pragma unroll
            for (int mf = 0; mf < 4; ++mf)
                af[mf] = *(const bf16x8*)&ab[(wm * 64 + mf * 16 + lr) * 64 + ks * 32 + lk * 8];
            #pragma unroll
            for (int nf = 0; nf < 4; ++nf)
                bfr[nf] = *(const bf16x8*)&bb[(wn * 64 + nf * 16 + lr) * 64 + ks * 32 + lk * 8];
            #pragma unroll
            for (int mf = 0; mf < 4; ++mf)
                #pragma unroll
                for (int nf = 0; nf < 4; ++nf)
                    acc[mf][nf] = __builtin_amdgcn_mfma_f32_16x16x32_bf16(
                        af[mf], bfr[nf], acc[mf][nf], 0, 0, 0);
        }
        __syncthreads();   // drains vmcnt(0)+lgkmcnt(0): prefetched tile landed
    }

    // epilogue: C/D layout col=lane&15, row=(lane>>4)*4+reg  [m89/m91 verified]
    #pragma unroll
    for (int mf = 0; mf < 4; ++mf) {
        const int row = bm + wm * 64 + mf * 16 + lk * 4;
        #pragma unroll
        for (int nf = 0; nf < 4; ++nf) {
            const int col = bn + wn * 64 + nf * 16 + lr;
            float* cp = C + (size_t)row * 512 + col;
            #pragma unroll
            for (int q = 0; q < 4; ++q) cp[(size_t)q * 512] = acc[mf][nf][q];
        }
    }
}

// ---------------------------------------------------------------------------
// GAT aggregation, one block (256 thr) per graph. All phases parallel:
// dots = 16 lanes/node x 16 nodes; softmax = atomic max-key + atomic sum;
// prefix scan = 16-lane parallel; accumulate = 1-edge-ahead pipelined.
// mode 1: relu + split-bf16 out [N,512]. mode 0: f32 out [N,256].
// ---------------------------------------------------------------------------
__global__ __launch_bounds__(256) void gat_aggregate(
    const float* __restrict__ hpre,
    const int* __restrict__ src_g, const int* __restrict__ dst_g,
    const float* __restrict__ att_src_g, const float* __restrict__ att_dst_g,
    const float* __restrict__ bias_g,
    float* __restrict__ outf, ushort* __restrict__ outs, int mode)
{
    __shared__ float  hsh[NPG][HC];       // 32 KB
    __shared__ float  asd[NPG][2][2];     // [n][head][src/dst]
    __shared__ float  elog[ETOT][2];      // raw logit -> exp value
    __shared__ int    esrc[ETOT], edst_[ETOT];
    __shared__ int    cnt[NPG + 1];       // bucket counts -> exclusive bases
    __shared__ int    off[NPG];
    __shared__ int    sordr[ETOT];
    __shared__ int    ssrc[ETOT];
    __shared__ float2 salpha[ETOT];       // normalized alphas, sorted order
    __shared__ uint   mkey[NPG][2];       // atomicMax keys (monotone map)
    __shared__ float  ssum[NPG][2];

    const int g = blockIdx.x;
    const int t = threadIdx.x;
    const int w = t >> 6, l = t & 63;
    const int nbase = g * NPG;

    // ---- phase A: stage features + edges, zero accumulators ----
    {
        const float4* hp = (const float4*)(hpre + (size_t)nbase * HC);
        float4* hs = (float4*)hsh;
        #pragma unroll
        for (int i = 0; i < 8; ++i) hs[t + i * 256] = hp[t + i * 256];
    }
    if (t < EPG) {
        esrc[t]  = src_g[(size_t)g * EPG + t] - nbase;
        edst_[t] = dst_g[(size_t)g * EPG + t] - nbase;
    } else if (t < ETOT) {
        int i = t - EPG;
        esrc[t] = i; edst_[t] = i;
    }
    if (t < NPG + 1) cnt[t] = 0;
    if (t < NPG * 2) { ((uint*)mkey)[t] = 0u; ((float*)ssum)[t] = 0.f; }
    __syncthreads();   // barrier 1

    // ---- phase B: dots, 16 lanes per node, all 16 nodes parallel ----
    {
        const int n = t >> 4, s = t & 15;
        float s0 = 0.f, s1 = 0.f, d0 = 0.f, d1 = 0.f;
        #pragma unroll
        for (int j = 0; j < 4; ++j) {
            const int c = s * 4 + j * 64;            // 2-way LDS aliasing only
            float4 h0 = *(const float4*)&hsh[n][c];
            float4 h1 = *(const float4*)&hsh[n][CH + c];
            float4 a0 = *(const float4*)&att_src_g[c];
            float4 a1 = *(const float4*)&att_src_g[CH + c];
            float4 b0 = *(const float4*)&att_dst_g[c];
            float4 b1 = *(const float4*)&att_dst_g[CH + c];
            s0 += h0.x * a0.x + h0.y * a0.y + h0.z * a0.z + h0.w * a0.w;
            s1 += h1.x * a1.x + h1.y * a1.y + h1.z * a1.z + h1.w * a1.w;
            d0 += h0.x * b0.x + h0.y * b0.y + h0.z * b0.z + h0.w * b0.w;
            d1 += h1.x * b1.x + h1.y * b1.y + h1.z * b1.z + h1.w * b1.w;
        }
        #pragma unroll
        for (int o = 1; o < 16; o <<= 1) {
            s0 += __shfl_xor(s0, o); s1 += __shfl_xor(s1, o);
            d0 += __shfl_xor(d0, o); d1 += __shfl_xor(d1, o);
        }
        if (s == 0) {
            asd[n][0][0] = s0; asd[n][1][0] = s1;
            asd[n][0][1] = d0; asd[n][1][1] = d1;
        }
    }
    if (t < ETOT) atomicAdd(&cnt[edst_[t]], 1);
    __syncthreads();   // barrier 2

    // ---- phase C: logits + per-bucket max (atomic key) + parallel scan ----
    for (int idx = t; idx < ETOT * 2; idx += 256) {
        int e = idx >> 1, hh = idx & 1;
        float lg = asd[esrc[e]][hh][0] + asd[edst_[e]][hh][1];
        lg = (lg > 0.f) ? lg : NEG * lg;
        elog[e][hh] = lg;
        atomicMax(&mkey[edst_[e]][hh], fkey(lg));
    }
    if (t < NPG) {          // 16-lane parallel exclusive scan (reads then writes)
        int excl = 0, own = 0;
        #pragma unroll
        for (int j = 0; j < NPG; ++j) {
            int c = cnt[j];
            if (j < t) excl += c;
            if (j == t) own = c;
        }
        off[t] = excl;
        cnt[t] = excl;
        if (t == NPG - 1) cnt[NPG] = excl + own;
    }
    __syncthreads();   // barrier 3

    // ---- phase D: exp + bucket sums; scatter-sort edge ids ----
    for (int idx = t; idx < ETOT * 2; idx += 256) {
        int e = idx >> 1, hh = idx & 1;
        int dn = edst_[e];
        float m = funkey(mkey[dn][hh]);
        float a = expf(elog[e][hh] - m);
        elog[e][hh] = a;
        atomicAdd(&ssum[dn][hh], a);
    }
    if (t < ETOT) { int p = atomicAdd(&off[edst_[t]], 1); sordr[p] = t; }
    __syncthreads();   // barrier 4

    // ---- phase E: normalized alphas into sorted order ----
    if (t < ETOT) {
        int e = sordr[t];
        int dn = edst_[e];
        ssrc[t] = esrc[e];
        float i0 = 1.0f / (ssum[dn][0] + 1e-16f);
        float i1 = 1.0f / (ssum[dn][1] + 1e-16f);
        salpha[t] = make_float2(elog[e][0] * i0, elog[e][1] * i1);
    }
    __syncthreads();   // barrier 5

    // ---- accumulate: wave w owns nodes {w,w+4,w+8,w+12}; lane owns ch 4l..4l+3
    const float4 bi = *(const float4*)&bias_g[4 * l];
    for (int nn = w; nn < NPG; nn += 4) {
        float4 a0 = make_float4(0.f, 0.f, 0.f, 0.f);
        float4 a1 = make_float4(0.f, 0.f, 0.f, 0.f);
        const int b0 = cnt[nn], b1 = cnt[nn + 1];
        int    s_nx  = ssrc[b0];
        float2 al_nx = salpha[b0];
        for (int i = b0; i < b1; ++i) {
            const int    s  = s_nx;
            const float2 al = al_nx;
            if (i + 1 < b1) { s_nx = ssrc[i + 1]; al_nx = salpha[i + 1]; }
            float4 h0 = *(const float4*)&hsh[s][4 * l];
            float4 h1 = *(const float4*)&hsh[s][CH + 4 * l];
            a0.x += al.x * h0.x; a0.y += al.x * h0.y;
            a0.z += al.x * h0.z; a0.w += al.x * h0.w;
            a1.x += al.y * h1.x; a1.y += al.y * h1.y;
            a1.z += al.y * h1.z; a1.w += al.y * h1.w;
        }
        float o0 = 0.5f * (a0.x + a1.x) + bi.x;
        float o1 = 0.5f * (a0.y + a1.y) + bi.y;
        float o2 = 0.5f * (a0.z + a1.z) + bi.z;
        float o3 = 0.5f * (a0.w + a1.w) + bi.w;
        if (mode) {   // relu + split-bf16 (feeds layer-2 MFMA GEMM)
            float v0 = fmaxf(o0, 0.f), v1 = fmaxf(o1, 0.f);
            float v2 = fmaxf(o2, 0.f), v3 = fmaxf(o3, 0.f);
            ushort4 hi, lo;
            hi.x = f2bf(v0); hi.y = f2bf(v1); hi.z = f2bf(v2); hi.w = f2bf(v3);
            lo.x = f2bf(v0 - bf2f(hi.x)); lo.y = f2bf(v1 - bf2f(hi.y));
            lo.z = f2bf(v2 - bf2f(hi.z)); lo.w = f2bf(v3 - bf2f(hi.w));
            ushort* dst = outs + (size_t)(nbase + nn) * 512;
            *(ushort4*)&dst[4 * l]      = hi;
            *(ushort4*)&dst[CH + 4 * l] = lo;
        } else {
            float* dst = outf + (size_t)(nbase + nn) * 256;
            *(float4*)&dst[4 * l] = make_float4(o0, o1, o2, o3);
        }
    }
}

// ---------------------------------------------------------------------------
// Per-graph attention pooling + linear classifier. One block per graph.
// ---------------------------------------------------------------------------
__global__ __launch_bounds__(256) void pool_classify(
    const float* __restrict__ h2,
    const float* __restrict__ w_att, const float* __restrict__ b_att,
    const float* __restrict__ Wc, const float* __restrict__ bc,
    float* __restrict__ outp)
{
    __shared__ float hsh[NPG][CH];
    __shared__ float wsh[CH];
    __shared__ float logit[NPG];
    __shared__ float red[16];

    const int g = blockIdx.x;
    const int t = threadIdx.x;

    const float4* hp = (const float4*)(h2 + (size_t)g * NPG * CH);
    float4* hs = (float4*)hsh;
    for (int i = t; i < NPG * CH / 4; i += 256) hs[i] = hp[i];
    if (t < 64) ((float4*)wsh)[t] = ((const float4*)w_att)[t];
    __syncthreads();

    {
        int n = t >> 4, sub = t & 15;
        float p = 0.f;
        const float* hv = hsh[n];
        #pragma unroll 4
        for (int c = sub * 16; c < sub * 16 + 16; ++c) p += hv[c] * wsh[c];
        p += __shfl_xor(p, 1); p += __shfl_xor(p, 2);
        p += __shfl_xor(p, 4); p += __shfl_xor(p, 8);
        if (sub == 0) logit[n] = p + b_att[0];
    }
    __syncthreads();

    float m = -1e30f;
    #pragma unroll
    for (int i = 0; i < NPG; ++i) m = fmaxf(m, logit[i]);
    float ssum = 0.f;
    #pragma unroll
    for (int i = 0; i < NPG; ++i) ssum += expf(logit[i] - m);
    float inv = 1.0f / (ssum + 1e-16f);

    float pooled = 0.f;
    #pragma unroll
    for (int n = 0; n < NPG; ++n)
        pooled += expf(logit[n] - m) * inv * hsh[n][t];

    float p0 = pooled * Wc[t];
    float p1 = pooled * Wc[CH + t];
    #pragma unroll
    for (int o = 32; o; o >>= 1) {
        p0 += __shfl_xor(p0, o);
        p1 += __shfl_xor(p1, o);
    }
    const int w = t >> 6, l = t & 63;
    if (l == 0) { red[w] = p0; red[8 + w] = p1; }
    __syncthreads();
    if (t == 0) {
        outp[(size_t)g * 2 + 0] = red[0] + red[1] + red[2] + red[3] + bc[0];
        outp[(size_t)g * 2 + 1] = red[8] + red[9] + red[10] + red[11] + bc[1];
    }
}

// ---------------------------------------------------------------------------
extern "C" void kernel_launch(void* const* d_in, const int* in_sizes, int n_in,
                              void* d_out, int out_size, void* d_ws, size_t ws_size,
                              hipStream_t stream)
{
    (void)in_sizes; (void)n_in; (void)out_size; (void)ws_size;
    const float* x    = (const float*)d_in[0];
    const int*   ei   = (const int*)d_in[1];     // [2,E]; harness delivers int32
    const float* W1   = (const float*)d_in[3];
    const float* as1  = (const float*)d_in[4];
    const float* ad1  = (const float*)d_in[5];
    const float* b1   = (const float*)d_in[6];
    const float* W2   = (const float*)d_in[7];
    const float* as2  = (const float*)d_in[8];
    const float* ad2  = (const float*)d_in[9];
    const float* b2   = (const float*)d_in[10];
    const float* watt = (const float*)d_in[11];
    const float* batt = (const float*)d_in[12];
    const float* Wc   = (const float*)d_in[13];
    const float* bc   = (const float*)d_in[14];
    float* out = (float*)d_out;

    const int* esrcp = ei;
    const int* edstp = ei + NEDGE;

    // ws: bufA 32MB (xs -> hs -> h2), bufB 64MB (hpre), weights 1MB  = 97MB
    const size_t MB = 1024 * 1024;
    ushort* bufA = (ushort*)d_ws;
    float*  hpre = (float*)((char*)d_ws + 32 * MB);
    ushort* w1s  = (ushort*)((char*)d_ws + 96 * MB);
    ushort* w2s  = w1s + 512 * 512;
    float*  h2   = (float*)bufA;

    convert_split<<<dim3(NNODES * 64 / 256), 256, 0, stream>>>(x, bufA, NNODES);
    convert_split<<<dim3(512 * 64 / 256), 256, 0, stream>>>(W1, w1s, 512);
    convert_split<<<dim3(512 * 64 / 256), 256, 0, stream>>>(W2, w2s, 512);

    gemm_split<<<dim3(1024), 256, 0, stream>>>(bufA, w1s, hpre);
    gat_aggregate<<<NGRAPH, 256, 0, stream>>>(hpre, esrcp, edstp, as1, ad1, b1,
                                              nullptr, bufA, 1);
    gemm_split<<<dim3(1024), 256, 0, stream>>>(bufA, w2s, hpre);
    gat_aggregate<<<NGRAPH, 256, 0, stream>>>(hpre, esrcp, edstp, as2, ad2, b2,
                                              h2, nullptr, 0);
    pool_classify<<<NGRAPH, 256, 0, stream>>>(h2, watt, batt, Wc, bc, out);
}

// Round 13
// 240.050 us; speedup vs baseline: 1.1922x; 1.1922x over previous
//
#include <hip/hip_runtime.h>
#include <hip/hip_bf16.h>

// Fused GAT (2 layers) + attention pooling + classifier for MI355X.
// Round 13: (1) revert GEMM to the measured round-10 256x256/BK64/8-wave
// geometry (round-12's 128x128/2-blk reshape REGRESSED: 54.4 vs 50.7 us --
// co-residency didn't materialize and total staging traffic doubled).
// (2) bf16x3 -> bf16x2: C = (A_hi+A_lo).B_hi = A.B_hi; dropped A.B_lo term
// ~2^-9 relative. KTILES 12 -> 8 (-33% GEMM work). absmax headroom 12.9x.

#define NGRAPH 2048
#define NPG    16
#define EPG    128
#define ETOT   (EPG + NPG)      // 144 edges incl. self loops
#define NNODES (NGRAPH * NPG)   // 32768
#define NEDGE  (NGRAPH * EPG)   // 262144
#define CH     256              // per-head channels
#define HC     512              // HEADS * CH
#define NEG    0.2f

#define KTILES 8                // bf16x2: passes {A_hi.B_hi, A_lo.B_hi}, BK=64

typedef __attribute__((ext_vector_type(8))) short bf16x8;
typedef __attribute__((ext_vector_type(4))) float f32x4;

__device__ __forceinline__ ushort f2bf(float f) {   // fp32 -> bf16 bits, RNE
    uint u = __float_as_uint(f);
    u += 0x7fffu + ((u >> 16) & 1u);
    return (ushort)(u >> 16);
}
__device__ __forceinline__ float bf2f(ushort b) {
    return __uint_as_float(((uint)b) << 16);
}
// monotone float<->uint key for atomicMax over arbitrary-sign floats
__device__ __forceinline__ uint fkey(float f) {
    uint u = __float_as_uint(f);
    return u ^ (uint)(((int)u >> 31) | (int)0x80000000u);
}
__device__ __forceinline__ float funkey(uint k) {
    uint u = (k & 0x80000000u) ? (k ^ 0x80000000u) : ~k;
    return __uint_as_float(u);
}

__device__ __forceinline__ void gll16(const void* g, void* l) {
    // async global->LDS, 16B/lane; LDS dest = wave-uniform base + lane*16
    __builtin_amdgcn_global_load_lds(
        (const __attribute__((address_space(1))) unsigned int*)g,
        (__attribute__((address_space(3))) unsigned int*)l, 16, 0, 0);
}

// ---------------------------------------------------------------------------
// fp32 [rows,256] -> split bf16 [rows,512]: hi plane at k<256, lo at k>=256
// ---------------------------------------------------------------------------
__global__ __launch_bounds__(256) void convert_split(
    const float* __restrict__ src, ushort* __restrict__ dst, int rows)
{
    int i = blockIdx.x * 256 + threadIdx.x;      // one thread per 4 elements
    if (i >= rows * 64) return;
    int r = i >> 6, c4 = (i & 63) << 2;
    float4 v = *(const float4*)&src[(size_t)r * 256 + c4];
    float vv[4] = {v.x, v.y, v.z, v.w};
    ushort4 hi, lo;
    ushort* hp = (ushort*)&hi; ushort* lp = (ushort*)&lo;
    #pragma unroll
    for (int q = 0; q < 4; ++q) {
        hp[q] = f2bf(vv[q]);
        lp[q] = f2bf(vv[q] - bf2f(hp[q]));
    }
    *(ushort4*)&dst[(size_t)r * 512 + c4]       = hi;
    *(ushort4*)&dst[(size_t)r * 512 + 256 + c4] = lo;
}

// ---------------------------------------------------------------------------
// C[M,512] (f32) = A[M,512-split].B_hi[512,256-of-512]^T
// BM=BN=256, BK=64, 512 threads (8 waves, 2Mx4N), wave tile 128x64.
// K-tiles 0..3: A_hi*B_hi, 4..7: A_lo*B_hi.  (bf16x2)
// 2-phase schedule: stage(kt+1 -> buf^1) || compute(kt from buf); one
// syncthreads per K-tile (drains vmcnt+lgkmcnt). Race-free by construction.
// ---------------------------------------------------------------------------
__global__ __launch_bounds__(512, 2) void gemm_split(
    const ushort* __restrict__ A2, const ushort* __restrict__ B2,
    float* __restrict__ C)
{
    __shared__ ushort Ash[2 * 256 * 64];   // 64 KB (double-buffered)
    __shared__ ushort Bsh[2 * 256 * 64];   // 64 KB

    const int t  = threadIdx.x;
    const int w  = t >> 6, l = t & 63;
    const int wm = w >> 2, wn = w & 3;     // 2 x 4 wave grid
    const int lr = l & 15;
    const int lk = l >> 4;                 // k sub-chunk (0..3) -> 8 elems each

    // bijective XCD-chunked swizzle: nwg=256 (%8==0). XCD x gets work-ids
    // [x*32, x*32+32) -> 16 consecutive A-panels per XCD -> A fetched 1x/XCD.
    const int work = (blockIdx.x & 7) * 32 + (blockIdx.x >> 3);
    const int bn = (work & 1) << 8;        // 2 col tiles
    const int bm = (work >> 1) << 8;       // 128 row tiles

    f32x4 acc[8][4];
    #pragma unroll
    for (int i = 0; i < 8; ++i)
        #pragma unroll
        for (int j = 0; j < 4; ++j)
            acc[i][j] = (f32x4){0.f, 0.f, 0.f, 0.f};

    auto stage = [&](int kt, int buf) {
        const int p    = kt >> 2;
        const int kk   = (kt & 3) << 6;               // 0,64,128,192
        const int aoff = ((p == 1) ? 256 : 0) + kk;   // A: lo plane on pass 1
        const int boff = kk;                          // B: hi plane only
        ushort* ab = Ash + buf * (256 * 64);
        ushort* bb = Bsh + buf * (256 * 64);
        #pragma unroll
        for (int i = 0; i < 4; ++i) {
            const int ci = i * 512 + t;               // 16B chunk id, 0..2047
            const int r  = ci >> 3;                   // tile row (8 chunks/row)
            const int cc = (ci & 7) << 3;             // k-elem offset in row
            gll16(A2 + (size_t)(bm + r) * 512 + aoff + cc, ab + ci * 8);
            gll16(B2 + (size_t)(bn + r) * 512 + boff + cc, bb + ci * 8);
        }
    };

    stage(0, 0);
    __syncthreads();
    for (int kt = 0; kt < KTILES; ++kt) {
        if (kt + 1 < KTILES) stage(kt + 1, (kt + 1) & 1);  // prefetch overlaps
        const ushort* ab = Ash + (kt & 1) * (256 * 64);
        const ushort* bb = Bsh + (kt & 1) * (256 * 64);
        #pragma unroll
        for (int ks = 0; ks < 2; ++ks) {
            bf16x8 af[8], bfr[4];
            #pragma unroll
            for (int mf = 0; mf < 8; ++mf)
                af[mf] = *(const bf16x8*)&ab[(wm * 128 + mf * 16 + lr) * 64 + ks * 32 + lk * 8];
            #pragma unroll
            for (int nf = 0; nf < 4; ++nf)
                bfr[nf] = *(const bf16x8*)&bb[(wn * 64 + nf * 16 + lr) * 64 + ks * 32 + lk * 8];
            #pragma unroll
            for (int mf = 0; mf < 8; ++mf)
                #pragma unroll
                for (int nf = 0; nf < 4; ++nf)
                    acc[mf][nf] = __builtin_amdgcn_mfma_f32_16x16x32_bf16(
                        af[mf], bfr[nf], acc[mf][nf], 0, 0, 0);
        }
        __syncthreads();   // drains vmcnt(0)+lgkmcnt(0): prefetched tile landed
    }

    // epilogue: C/D layout col=lane&15, row=(lane>>4)*4+reg  [m89/m91 verified]
    #pragma unroll
    for (int mf = 0; mf < 8; ++mf) {
        const int row = bm + wm * 128 + mf * 16 + lk * 4;
        #pragma unroll
        for (int nf = 0; nf < 4; ++nf) {
            const int col = bn + wn * 64 + nf * 16 + lr;
            float* cp = C + (size_t)row * 512 + col;
            #pragma unroll
            for (int q = 0; q < 4; ++q) cp[(size_t)q * 512] = acc[mf][nf][q];
        }
    }
}

// ---------------------------------------------------------------------------
// GAT aggregation, one block (256 thr) per graph. All phases parallel:
// dots = 16 lanes/node x 16 nodes; softmax = atomic max-key + atomic sum;
// prefix scan = 16-lane parallel; accumulate = 1-edge-ahead pipelined.
// mode 1: relu + split-bf16 out [N,512]. mode 0: f32 out [N,256].
// ---------------------------------------------------------------------------
__global__ __launch_bounds__(256) void gat_aggregate(
    const float* __restrict__ hpre,
    const int* __restrict__ src_g, const int* __restrict__ dst_g,
    const float* __restrict__ att_src_g, const float* __restrict__ att_dst_g,
    const float* __restrict__ bias_g,
    float* __restrict__ outf, ushort* __restrict__ outs, int mode)
{
    __shared__ float  hsh[NPG][HC];       // 32 KB
    __shared__ float  asd[NPG][2][2];     // [n][head][src/dst]
    __shared__ float  elog[ETOT][2];      // raw logit -> exp value
    __shared__ int    esrc[ETOT], edst_[ETOT];
    __shared__ int    cnt[NPG + 1];       // bucket counts -> exclusive bases
    __shared__ int    off[NPG];
    __shared__ int    sordr[ETOT];
    __shared__ int    ssrc[ETOT];
    __shared__ float2 salpha[ETOT];       // normalized alphas, sorted order
    __shared__ uint   mkey[NPG][2];       // atomicMax keys (monotone map)
    __shared__ float  ssum[NPG][2];

    const int g = blockIdx.x;
    const int t = threadIdx.x;
    const int w = t >> 6, l = t & 63;
    const int nbase = g * NPG;

    // ---- phase A: stage features + edges, zero accumulators ----
    {
        const float4* hp = (const float4*)(hpre + (size_t)nbase * HC);
        float4* hs = (float4*)hsh;
        #pragma unroll
        for (int i = 0; i < 8; ++i) hs[t + i * 256] = hp[t + i * 256];
    }
    if (t < EPG) {
        esrc[t]  = src_g[(size_t)g * EPG + t] - nbase;
        edst_[t] = dst_g[(size_t)g * EPG + t] - nbase;
    } else if (t < ETOT) {
        int i = t - EPG;
        esrc[t] = i; edst_[t] = i;
    }
    if (t < NPG + 1) cnt[t] = 0;
    if (t < NPG * 2) { ((uint*)mkey)[t] = 0u; ((float*)ssum)[t] = 0.f; }
    __syncthreads();   // barrier 1

    // ---- phase B: dots, 16 lanes per node, all 16 nodes parallel ----
    {
        const int n = t >> 4, s = t & 15;
        float s0 = 0.f, s1 = 0.f, d0 = 0.f, d1 = 0.f;
        #pragma unroll
        for (int j = 0; j < 4; ++j) {
            const int c = s * 4 + j * 64;            // 2-way LDS aliasing only
            float4 h0 = *(const float4*)&hsh[n][c];
            float4 h1 = *(const float4*)&hsh[n][CH + c];
            float4 a0 = *(const float4*)&att_src_g[c];
            float4 a1 = *(const float4*)&att_src_g[CH + c];
            float4 b0 = *(const float4*)&att_dst_g[c];
            float4 b1 = *(const float4*)&att_dst_g[CH + c];
            s0 += h0.x * a0.x + h0.y * a0.y + h0.z * a0.z + h0.w * a0.w;
            s1 += h1.x * a1.x + h1.y * a1.y + h1.z * a1.z + h1.w * a1.w;
            d0 += h0.x * b0.x + h0.y * b0.y + h0.z * b0.z + h0.w * b0.w;
            d1 += h1.x * b1.x + h1.y * b1.y + h1.z * b1.z + h1.w * b1.w;
        }
        #pragma unroll
        for (int o = 1; o < 16; o <<= 1) {
            s0 += __shfl_xor(s0, o); s1 += __shfl_xor(s1, o);
            d0 += __shfl_xor(d0, o); d1 += __shfl_xor(d1, o);
        }
        if (s == 0) {
            asd[n][0][0] = s0; asd[n][1][0] = s1;
            asd[n][0][1] = d0; asd[n][1][1] = d1;
        }
    }
    if (t < ETOT) atomicAdd(&cnt[edst_[t]], 1);
    __syncthreads();   // barrier 2

    // ---- phase C: logits + per-bucket max (atomic key) + parallel scan ----
    for (int idx = t; idx < ETOT * 2; idx += 256) {
        int e = idx >> 1, hh = idx & 1;
        float lg = asd[esrc[e]][hh][0] + asd[edst_[e]][hh][1];
        lg = (lg > 0.f) ? lg : NEG * lg;
        elog[e][hh] = lg;
        atomicMax(&mkey[edst_[e]][hh], fkey(lg));
    }
    if (t < NPG) {          // 16-lane parallel exclusive scan (reads then writes)
        int excl = 0, own = 0;
        #pragma unroll
        for (int j = 0; j < NPG; ++j) {
            int c = cnt[j];
            if (j < t) excl += c;
            if (j == t) own = c;
        }
        off[t] = excl;
        cnt[t] = excl;
        if (t == NPG - 1) cnt[NPG] = excl + own;
    }
    __syncthreads();   // barrier 3

    // ---- phase D: exp + bucket sums; scatter-sort edge ids ----
    for (int idx = t; idx < ETOT * 2; idx += 256) {
        int e = idx >> 1, hh = idx & 1;
        int dn = edst_[e];
        float m = funkey(mkey[dn][hh]);
        float a = expf(elog[e][hh] - m);
        elog[e][hh] = a;
        atomicAdd(&ssum[dn][hh], a);
    }
    if (t < ETOT) { int p = atomicAdd(&off[edst_[t]], 1); sordr[p] = t; }
    __syncthreads();   // barrier 4

    // ---- phase E: normalized alphas into sorted order ----
    if (t < ETOT) {
        int e = sordr[t];
        int dn = edst_[e];
        ssrc[t] = esrc[e];
        float i0 = 1.0f / (ssum[dn][0] + 1e-16f);
        float i1 = 1.0f / (ssum[dn][1] + 1e-16f);
        salpha[t] = make_float2(elog[e][0] * i0, elog[e][1] * i1);
    }
    __syncthreads();   // barrier 5

    // ---- accumulate: wave w owns nodes {w,w+4,w+8,w+12}; lane owns ch 4l..4l+3
    const float4 bi = *(const float4*)&bias_g[4 * l];
    for (int nn = w; nn < NPG; nn += 4) {
        float4 a0 = make_float4(0.f, 0.f, 0.f, 0.f);
        float4 a1 = make_float4(0.f, 0.f, 0.f, 0.f);
        const int b0 = cnt[nn], b1 = cnt[nn + 1];
        int    s_nx  = ssrc[b0];
        float2 al_nx = salpha[b0];
        for (int i = b0; i < b1; ++i) {
            const int    s  = s_nx;
            const float2 al = al_nx;
            if (i + 1 < b1) { s_nx = ssrc[i + 1]; al_nx = salpha[i + 1]; }
            float4 h0 = *(const float4*)&hsh[s][4 * l];
            float4 h1 = *(const float4*)&hsh[s][CH + 4 * l];
            a0.x += al.x * h0.x; a0.y += al.x * h0.y;
            a0.z += al.x * h0.z; a0.w += al.x * h0.w;
            a1.x += al.y * h1.x; a1.y += al.y * h1.y;
            a1.z += al.y * h1.z; a1.w += al.y * h1.w;
        }
        float o0 = 0.5f * (a0.x + a1.x) + bi.x;
        float o1 = 0.5f * (a0.y + a1.y) + bi.y;
        float o2 = 0.5f * (a0.z + a1.z) + bi.z;
        float o3 = 0.5f * (a0.w + a1.w) + bi.w;
        if (mode) {   // relu + split-bf16 (feeds layer-2 MFMA GEMM)
            float v0 = fmaxf(o0, 0.f), v1 = fmaxf(o1, 0.f);
            float v2 = fmaxf(o2, 0.f), v3 = fmaxf(o3, 0.f);
            ushort4 hi, lo;
            hi.x = f2bf(v0); hi.y = f2bf(v1); hi.z = f2bf(v2); hi.w = f2bf(v3);
            lo.x = f2bf(v0 - bf2f(hi.x)); lo.y = f2bf(v1 - bf2f(hi.y));
            lo.z = f2bf(v2 - bf2f(hi.z)); lo.w = f2bf(v3 - bf2f(hi.w));
            ushort* dst = outs + (size_t)(nbase + nn) * 512;
            *(ushort4*)&dst[4 * l]      = hi;
            *(ushort4*)&dst[CH + 4 * l] = lo;
        } else {
            float* dst = outf + (size_t)(nbase + nn) * 256;
            *(float4*)&dst[4 * l] = make_float4(o0, o1, o2, o3);
        }
    }
}

// ---------------------------------------------------------------------------
// Per-graph attention pooling + linear classifier. One block per graph.
// ---------------------------------------------------------------------------
__global__ __launch_bounds__(256) void pool_classify(
    const float* __restrict__ h2,
    const float* __restrict__ w_att, const float* __restrict__ b_att,
    const float* __restrict__ Wc, const float* __restrict__ bc,
    float* __restrict__ outp)
{
    __shared__ float hsh[NPG][CH];
    __shared__ float wsh[CH];
    __shared__ float logit[NPG];
    __shared__ float red[16];

    const int g = blockIdx.x;
    const int t = threadIdx.x;

    const float4* hp = (const float4*)(h2 + (size_t)g * NPG * CH);
    float4* hs = (float4*)hsh;
    for (int i = t; i < NPG * CH / 4; i += 256) hs[i] = hp[i];
    if (t < 64) ((float4*)wsh)[t] = ((const float4*)w_att)[t];
    __syncthreads();

    {
        int n = t >> 4, sub = t & 15;
        float p = 0.f;
        const float* hv = hsh[n];
        #pragma unroll 4
        for (int c = sub * 16; c < sub * 16 + 16; ++c) p += hv[c] * wsh[c];
        p += __shfl_xor(p, 1); p += __shfl_xor(p, 2);
        p += __shfl_xor(p, 4); p += __shfl_xor(p, 8);
        if (sub == 0) logit[n] = p + b_att[0];
    }
    __syncthreads();

    float m = -1e30f;
    #pragma unroll
    for (int i = 0; i < NPG; ++i) m = fmaxf(m, logit[i]);
    float ssum = 0.f;
    #pragma unroll
    for (int i = 0; i < NPG; ++i) ssum += expf(logit[i] - m);
    float inv = 1.0f / (ssum + 1e-16f);

    float pooled = 0.f;
    #pragma unroll
    for (int n = 0; n < NPG; ++n)
        pooled += expf(logit[n] - m) * inv * hsh[n][t];

    float p0 = pooled * Wc[t];
    float p1 = pooled * Wc[CH + t];
    #pragma unroll
    for (int o = 32; o; o >>= 1) {
        p0 += __shfl_xor(p0, o);
        p1 += __shfl_xor(p1, o);
    }
    const int w = t >> 6, l = t & 63;
    if (l == 0) { red[w] = p0; red[8 + w] = p1; }
    __syncthreads();
    if (t == 0) {
        outp[(size_t)g * 2 + 0] = red[0] + red[1] + red[2] + red[3] + bc[0];
        outp[(size_t)g * 2 + 1] = red[8] + red[9] + red[10] + red[11] + bc[1];
    }
}

// ---------------------------------------------------------------------------
extern "C" void kernel_launch(void* const* d_in, const int* in_sizes, int n_in,
                              void* d_out, int out_size, void* d_ws, size_t ws_size,
                              hipStream_t stream)
{
    (void)in_sizes; (void)n_in; (void)out_size; (void)ws_size;
    const float* x    = (const float*)d_in[0];
    const int*   ei   = (const int*)d_in[1];     // [2,E]; harness delivers int32
    const float* W1   = (const float*)d_in[3];
    const float* as1  = (const float*)d_in[4];
    const float* ad1  = (const float*)d_in[5];
    const float* b1   = (const float*)d_in[6];
    const float* W2   = (const float*)d_in[7];
    const float* as2  = (const float*)d_in[8];
    const float* ad2  = (const float*)d_in[9];
    const float* b2   = (const float*)d_in[10];
    const float* watt = (const float*)d_in[11];
    const float* batt = (const float*)d_in[12];
    const float* Wc   = (const float*)d_in[13];
    const float* bc   = (const float*)d_in[14];
    float* out = (float*)d_out;

    const int* esrcp = ei;
    const int* edstp = ei + NEDGE;

    // ws: bufA 32MB (xs -> hs -> h2), bufB 64MB (hpre), weights 1MB  = 97MB
    const size_t MB = 1024 * 1024;
    ushort* bufA = (ushort*)d_ws;
    float*  hpre = (float*)((char*)d_ws + 32 * MB);
    ushort* w1s  = (ushort*)((char*)d_ws + 96 * MB);
    ushort* w2s  = w1s + 512 * 512;
    float*  h2   = (float*)bufA;

    convert_split<<<dim3(NNODES * 64 / 256), 256, 0, stream>>>(x, bufA, NNODES);
    convert_split<<<dim3(512 * 64 / 256), 256, 0, stream>>>(W1, w1s, 512);
    convert_split<<<dim3(512 * 64 / 256), 256, 0, stream>>>(W2, w2s, 512);

    gemm_split<<<dim3(256), 512, 0, stream>>>(bufA, w1s, hpre);
    gat_aggregate<<<NGRAPH, 256, 0, stream>>>(hpre, esrcp, edstp, as1, ad1, b1,
                                              nullptr, bufA, 1);
    gemm_split<<<dim3(256), 512, 0, stream>>>(bufA, w2s, hpre);
    gat_aggregate<<<NGRAPH, 256, 0, stream>>>(hpre, esrcp, edstp, as2, ad2, b2,
                                              h2, nullptr, 0);
    pool_classify<<<NGRAPH, 256, 0, stream>>>(h2, watt, batt, Wc, bc, out);
}